// Round 1
// baseline (253.597 us; speedup 1.0000x reference)
//
#include <hip/hip_runtime.h>
#include <cstdint>

#define NB 256       // batch
#define ND 2048      // feature dim
#define NP 8192      // proxies
#define NEG_INF_F (-1e30f)
#define INV_TEMP (1.0f/0.07f)

typedef __attribute__((ext_vector_type(8))) short          short8;
typedef __attribute__((ext_vector_type(8))) unsigned short ushort8;
typedef __attribute__((ext_vector_type(4))) float          floatx4;

__device__ __forceinline__ unsigned short f2bf(float f) {
  unsigned u = __float_as_uint(f);
  return (unsigned short)((u + 0x7fffu + ((u >> 16) & 1u)) >> 16);  // RNE
}

// ---------------- f32 -> bf16 conversion (8 elems / thread) ----------------
__global__ __launch_bounds__(256)
void cvt_kernel(const float* __restrict__ in, unsigned short* __restrict__ out, int n8) {
  int i = blockIdx.x * 256 + threadIdx.x;
  if (i >= n8) return;
  const float4* p = (const float4*)in + 2 * (size_t)i;
  float4 a = p[0], b = p[1];
  ushort8 r;
  r[0] = f2bf(a.x); r[1] = f2bf(a.y); r[2] = f2bf(a.z); r[3] = f2bf(a.w);
  r[4] = f2bf(b.x); r[5] = f2bf(b.y); r[6] = f2bf(b.z); r[7] = f2bf(b.w);
  *(ushort8*)(out + 8 * (size_t)i) = r;
}

// ---------------- GEMM: S[i][p] = sum_k F[i][k] * Mem[p][k] ----------------
// BM=64, BN=128, BK=32, split-K=2. 256 threads = 4 waves; wave w computes
// 64 rows x cols [32w,32w+32) as 4x2 16x16x32 MFMA fragments.
#define GLOAD_LDS16(g, l) __builtin_amdgcn_global_load_lds( \
  (const __attribute__((address_space(1))) unsigned int*)(g), \
  (__attribute__((address_space(3))) unsigned int*)(l), 16, 0, 0)

__global__ __launch_bounds__(256, 2)
void gemm_kernel(const unsigned short* __restrict__ Fb,
                 const unsigned short* __restrict__ Mb,
                 float* __restrict__ Sout) {
  __shared__ unsigned short sA[2][64 * 32];    // 4 KB each
  __shared__ unsigned short sB[2][128 * 32];   // 8 KB each
  const int tid  = threadIdx.x;
  const int wave = tid >> 6;
  const int lane = tid & 63;
  const int frow = lane & 15;
  const int kg   = lane >> 4;
  const int bn0  = blockIdx.x * 128;
  const int bm0  = blockIdx.y * 64;
  const int kofs = blockIdx.z * 1024;

  // staging: thread t owns LDS linear slot t (16B): row = t>>2, chunk = t&3.
  // source chunk is XOR-swizzled so ds_read side can de-conflict banks.
  const int arow = tid >> 2;
  const int achk = tid & 3;
  const int cg   = (achk ^ ((arow >> 1) & 3)) * 8;   // swizzled k-chunk (elems)

  const unsigned short* gA  = Fb + (size_t)(bm0 + arow) * ND + kofs + cg;
  const unsigned short* gB0 = Mb + (size_t)(bn0 + arow) * ND + kofs + cg;
  const unsigned short* gB1 = Mb + (size_t)(bn0 + 64 + arow) * ND + kofs + cg;

  floatx4 acc[4][2];
  #pragma unroll
  for (int m = 0; m < 4; ++m)
    #pragma unroll
    for (int n = 0; n < 2; ++n)
      #pragma unroll
      for (int r = 0; r < 4; ++r) acc[m][n][r] = 0.f;

  // LDS fragment read offsets (bf16 elements), same swizzle as source
  int offA[4], offB[2];
  #pragma unroll
  for (int m = 0; m < 4; ++m) {
    int rl = 16 * m + frow;
    offA[m] = rl * 32 + ((kg ^ ((rl >> 1) & 3)) << 3);
  }
  #pragma unroll
  for (int n = 0; n < 2; ++n) {
    int rl = wave * 32 + 16 * n + frow;
    offB[n] = rl * 32 + ((kg ^ ((rl >> 1) & 3)) << 3);
  }

  auto stage = [&](int buf, int kt) {
    int kk = kt * 32;
    GLOAD_LDS16(gA  + kk, &sA[buf][wave * 512]);
    GLOAD_LDS16(gB0 + kk, &sB[buf][wave * 512]);
    GLOAD_LDS16(gB1 + kk, &sB[buf][2048 + wave * 512]);
  };
  auto compute = [&](int buf) {
    short8 af[4], bf[2];
    #pragma unroll
    for (int m = 0; m < 4; ++m) af[m] = *(const short8*)&sA[buf][offA[m]];
    #pragma unroll
    for (int n = 0; n < 2; ++n) bf[n] = *(const short8*)&sB[buf][offB[n]];
    #pragma unroll
    for (int m = 0; m < 4; ++m)
      #pragma unroll
      for (int n = 0; n < 2; ++n)
        acc[m][n] = __builtin_amdgcn_mfma_f32_16x16x32_bf16(af[m], bf[n], acc[m][n], 0, 0, 0);
  };

  stage(0, 0);
  __syncthreads();
  int cur = 0;
  for (int kt = 0; kt < 31; ++kt) {     // 1024 / 32 = 32 K-steps per slice
    stage(cur ^ 1, kt + 1);
    compute(cur);
    __syncthreads();
    cur ^= 1;
  }
  compute(cur);

  float* Sp = Sout + (size_t)blockIdx.z * ((size_t)NB * NP);
  #pragma unroll
  for (int m = 0; m < 4; ++m) {
    int row = bm0 + 16 * m + 4 * kg;           // C/D: row=(lane>>4)*4+r
    #pragma unroll
    for (int n = 0; n < 2; ++n) {
      int col = bn0 + wave * 32 + 16 * n + frow; // C/D: col=lane&15
      #pragma unroll
      for (int r = 0; r < 4; ++r)
        Sp[(size_t)(row + r) * NP + col] = acc[m][n][r];
    }
  }
}

// ---------------- block reductions (256 threads = 4 waves) ----------------
__device__ __forceinline__ float blk_sum(float x, float* red) {
  #pragma unroll
  for (int o = 32; o; o >>= 1) x += __shfl_xor(x, o);
  if ((threadIdx.x & 63) == 0) red[threadIdx.x >> 6] = x;
  __syncthreads();
  float r = red[0] + red[1] + red[2] + red[3];
  __syncthreads();
  return r;
}
__device__ __forceinline__ float blk_max(float x, float* red) {
  #pragma unroll
  for (int o = 32; o; o >>= 1) x = fmaxf(x, __shfl_xor(x, o));
  if ((threadIdx.x & 63) == 0) red[threadIdx.x >> 6] = x;
  __syncthreads();
  float r = fmaxf(fmaxf(red[0], red[1]), fmaxf(red[2], red[3]));
  __syncthreads();
  return r;
}

// ---------------- per-row: intra CE, top-k threshold, inter loss ----------
__global__ __launch_bounds__(256)
void row_kernel(const float* __restrict__ S,
                const int* __restrict__ label,
                const int* __restrict__ camid,
                const int* __restrict__ pcl,
                const int* __restrict__ epoch_p,
                const int* __restrict__ ilep_p,
                const int* __restrict__ k_p,
                float* __restrict__ ce_out,
                float* __restrict__ li_out) {
  __shared__ float red[4];
  const int i = blockIdx.x;
  const int t = threadIdx.x;
  const float* r0 = S + (size_t)i * NP;                     // K-slice 0
  const float* r1 = S + (size_t)NB * NP + (size_t)i * NP;   // K-slice 1
  float v[32];
  #pragma unroll
  for (int jj = 0; jj < 8; ++jj) {
    float4 a = *(const float4*)(r0 + jj * 1024 + 4 * t);
    float4 b = *(const float4*)(r1 + jj * 1024 + 4 * t);
    v[4*jj+0] = a.x + b.x; v[4*jj+1] = a.y + b.y;
    v[4*jj+2] = a.z + b.z; v[4*jj+3] = a.w + b.w;
  }
  const int camI = camid[i], clI = pcl[i], lab = label[i];
  // element j of this thread is proxy p = (j>>2)*1024 + 4t + (j&3)

  // ---- intra-camera CE ----
  float m1 = NEG_INF_F;
  #pragma unroll
  for (int j = 0; j < 32; ++j) {
    int p = ((j >> 2) << 10) | (t << 2) | (j & 3);
    if ((p & 7) == camI) m1 = fmaxf(m1, v[j]);
  }
  m1 = blk_max(m1, red);
  float s1 = 0.f, tg = 0.f;
  #pragma unroll
  for (int j = 0; j < 32; ++j) {
    int p = ((j >> 2) << 10) | (t << 2) | (j & 3);
    if ((p & 7) == camI) s1 += __expf((v[j] - m1) * INV_TEMP);
    if (p == lab) tg = v[j];
  }
  s1 = blk_sum(s1, red);
  tg = blk_sum(tg, red);
  if (t == 0) ce_out[i] = m1 * INV_TEMP + __logf(s1) - tg * INV_TEMP;

  // ---- inter-camera loss ----
  float li = 0.f;
  if (epoch_p[0] >= ilep_p[0]) {
    const int kneg = k_p[0];
    unsigned kk[32];
    #pragma unroll
    for (int j = 0; j < 32; ++j) {   // monotonic f32 -> u32 key
      unsigned u = __float_as_uint(v[j]);
      kk[j] = (u & 0x80000000u) ? ~u : (u | 0x80000000u);
    }
    // exact k-th largest among negatives: greedy MSB->LSB bit build
    unsigned tstar = 0u;
    for (int b = 31; b >= 0; --b) {
      unsigned cand = tstar | (1u << b);
      float c = 0.f;
      #pragma unroll
      for (int j = 0; j < 32; ++j) {
        int p = ((j >> 2) << 10) | (t << 2) | (j & 3);
        if (((p >> 3) != clI) && (kk[j] >= cand)) c += 1.f;
      }
      c = blk_sum(c, red);
      if (c >= (float)kneg) tstar = cand;
    }
    float thr = __uint_as_float((tstar & 0x80000000u) ? (tstar ^ 0x80000000u) : ~tstar);

    float m2 = NEG_INF_F;
    #pragma unroll
    for (int j = 0; j < 32; ++j) {
      int p = ((j >> 2) << 10) | (t << 2) | (j & 3);
      bool pos  = ((p >> 3) == clI) && ((p & 7) != camI);
      bool keep = ((p >> 3) != clI) && (v[j] < thr);   // strict <, ties dropped (matches ref)
      if (pos || keep) m2 = fmaxf(m2, v[j]);
    }
    m2 = blk_max(m2, red);
    float s2 = 0.f, sp = 0.f, card = 0.f;
    #pragma unroll
    for (int j = 0; j < 32; ++j) {
      int p = ((j >> 2) << 10) | (t << 2) | (j & 3);
      bool pos  = ((p >> 3) == clI) && ((p & 7) != camI);
      bool keep = ((p >> 3) != clI) && (v[j] < thr);
      if (pos || keep) s2 += __expf((v[j] - m2) * INV_TEMP);
      if (pos) { sp += v[j]; card += 1.f; }
    }
    s2 = blk_sum(s2, red);
    sp = blk_sum(sp, red);
    card = blk_sum(card, red);
    float lse2 = m2 * INV_TEMP + __logf(s2);
    li = (card > 0.f) ? -(sp * INV_TEMP - card * lse2) / card : 0.f;
  }
  if (t == 0) li_out[i] = li;
}

// ---------------- per-camera segment means -> scalar loss -----------------
__global__ void finalize_kernel(const float* __restrict__ ce,
                                const float* __restrict__ li,
                                const int* __restrict__ camid,
                                const int* __restrict__ epoch_p,
                                const int* __restrict__ ilep_p,
                                float* __restrict__ out) {
  __shared__ float part[8];
  int t = threadIdx.x;
  if (t < 8) {
    float cnt = 0.f, a = 0.f, b = 0.f;
    for (int i = 0; i < NB; ++i)
      if (camid[i] == t) { cnt += 1.f; a += ce[i]; b += li[i]; }
    float p = 0.f;
    if (cnt > 0.f) {
      p = a / cnt;
      if (epoch_p[0] >= ilep_p[0]) p += 0.5f * b / cnt;
    }
    part[t] = p;
  }
  __syncthreads();
  if (t == 0) {
    float l = 0.f;
    for (int c = 0; c < 8; ++c) l += part[c];
    out[0] = l;
  }
}

// ---------------- sequential EMA scatter update (scan semantics) ----------
__global__ __launch_bounds__(256)
void ema_kernel(const float* __restrict__ feat,
                const float* __restrict__ mem,
                const int* __restrict__ label,
                float* __restrict__ outmem) {
  __shared__ float red[4];
  const int b = blockIdx.x;
  const int t = threadIdx.x;
  const int y = label[b];
  for (int j = 0; j < b; ++j)
    if (label[j] == y) return;           // only first occurrence owns the chain
  float m[8];
  #pragma unroll
  for (int q = 0; q < 8; ++q) m[q] = mem[(size_t)y * ND + q * 256 + t];
  for (int i = b; i < NB; ++i) {
    if (label[i] != y) continue;         // block-uniform
    float ss = 0.f;
    #pragma unroll
    for (int q = 0; q < 8; ++q) {
      m[q] = 0.2f * m[q] + 0.8f * feat[(size_t)i * ND + q * 256 + t];
      ss += m[q] * m[q];
    }
    ss = blk_sum(ss, red);
    float inv = 1.f / sqrtf(ss);
    #pragma unroll
    for (int q = 0; q < 8; ++q) m[q] *= inv;
  }
  #pragma unroll
  for (int q = 0; q < 8; ++q) outmem[(size_t)y * ND + q * 256 + t] = m[q];
}

// --------------------------------------------------------------------------
extern "C" void kernel_launch(void* const* d_in, const int* in_sizes, int n_in,
                              void* d_out, int out_size, void* d_ws, size_t ws_size,
                              hipStream_t stream) {
  const float* feat = (const float*)d_in[0];
  const float* mem  = (const float*)d_in[1];
  const int* lab    = (const int*)d_in[2];
  const int* cam    = (const int*)d_in[3];
  const int* pcl    = (const int*)d_in[4];
  const int* ep     = (const int*)d_in[7];
  const int* ilep   = (const int*)d_in[8];
  const int* kp     = (const int*)d_in[9];
  float* out = (float*)d_out;

  // scratch lives in the d_out/new_memory region; it is fully dead before the
  // final memcpy+EMA overwrite it. d_ws is unused -> no ws_size assumptions.
  unsigned short* Mb = (unsigned short*)(out + 4);        // 32 MB bf16 memory
  float*          S  = out + 8388612;                      // 2 x 8 MB split-K partials
  unsigned short* Fb = (unsigned short*)(out + 12582916);  // 1 MB bf16 feats
  float*          ce = out + 12845060;                     // 256 floats
  float*          li = out + 12845316;                     // 256 floats

  cvt_kernel<<<256, 256, 0, stream>>>(feat, Fb, (NB * ND) / 8);
  cvt_kernel<<<8192, 256, 0, stream>>>(mem, Mb, (NP * ND) / 8);
  gemm_kernel<<<dim3(NP / 128, NB / 64, 2), 256, 0, stream>>>(Fb, Mb, S);
  row_kernel<<<NB, 256, 0, stream>>>(S, lab, cam, pcl, ep, ilep, kp, ce, li);
  finalize_kernel<<<1, 64, 0, stream>>>(ce, li, cam, ep, ilep, out);
  hipMemcpyAsync(out + 1, mem, (size_t)NP * ND * sizeof(float),
                 hipMemcpyDeviceToDevice, stream);
  ema_kernel<<<NB, 256, 0, stream>>>(feat, mem, lab, out + 1);
}

// Round 2
// 207.205 us; speedup vs baseline: 1.2239x; 1.2239x over previous
//
#include <hip/hip_runtime.h>
#include <cstdint>

#define NB 256       // batch
#define ND 2048      // feature dim
#define NP 8192      // proxies
#define NEG_INF_F (-1e30f)
#define INV_TEMP (1.0f/0.07f)

typedef __attribute__((ext_vector_type(8))) short          short8;
typedef __attribute__((ext_vector_type(8))) unsigned short ushort8;
typedef __attribute__((ext_vector_type(4))) float          floatx4;

__device__ __forceinline__ unsigned short f2bf(float f) {
  unsigned u = __float_as_uint(f);
  return (unsigned short)((u + 0x7fffu + ((u >> 16) & 1u)) >> 16);  // RNE
}

// ---- prep: mem -> bf16 + f32 copy into d_out; feat -> bf16 ---------------
__global__ __launch_bounds__(256)
void prep_kernel(const float* __restrict__ mem, const float* __restrict__ feat,
                 unsigned short* __restrict__ Mb, unsigned short* __restrict__ Fb,
                 float* __restrict__ memcopy /* = out+1, only 4B-aligned */) {
  const int b = blockIdx.x, t = threadIdx.x;
  if (b < 8192) {
    const float4* src = (const float4*)(mem + (size_t)b * ND) + 2 * t;
    float4 a = src[0], c = src[1];
    ushort8 r;
    r[0]=f2bf(a.x); r[1]=f2bf(a.y); r[2]=f2bf(a.z); r[3]=f2bf(a.w);
    r[4]=f2bf(c.x); r[5]=f2bf(c.y); r[6]=f2bf(c.z); r[7]=f2bf(c.w);
    *(ushort8*)(Mb + (size_t)b * ND + 8 * t) = r;
    float* dst = memcopy + (size_t)b * ND + 8 * t;   // 4B-aligned only -> dwords
    dst[0]=a.x; dst[1]=a.y; dst[2]=a.z; dst[3]=a.w;
    dst[4]=c.x; dst[5]=c.y; dst[6]=c.z; dst[7]=c.w;
  } else {
    const int i = (b - 8192) * 256 + t;              // 8-elem group, < 65536
    const float4* src = (const float4*)feat + 2 * (size_t)i;
    float4 a = src[0], c = src[1];
    ushort8 r;
    r[0]=f2bf(a.x); r[1]=f2bf(a.y); r[2]=f2bf(a.z); r[3]=f2bf(a.w);
    r[4]=f2bf(c.x); r[5]=f2bf(c.y); r[6]=f2bf(c.z); r[7]=f2bf(c.w);
    *(ushort8*)(Fb + 8 * (size_t)i) = r;
  }
}

// ---------------- GEMM: S[i][p] = sum_k F[i][k] * Mem[p][k] ----------------
// BM=64, BN=128, BK=64, split-K=2. 256 threads = 4 waves; wave w computes
// 64 rows x cols [32w,32w+32) as 4x2 fragments, 2 k-frags per step.
#define GLOAD_LDS16(g, l) __builtin_amdgcn_global_load_lds( \
  (const __attribute__((address_space(1))) unsigned int*)(g), \
  (__attribute__((address_space(3))) unsigned int*)(l), 16, 0, 0)

__global__ __launch_bounds__(256, 2)
void gemm_kernel(const unsigned short* __restrict__ Fb,
                 const unsigned short* __restrict__ Mb,
                 float* __restrict__ Sout) {
  __shared__ unsigned short sA[2][64 * 64];    // 8 KB each
  __shared__ unsigned short sB[2][128 * 64];   // 16 KB each
  const int tid  = threadIdx.x;
  const int wave = tid >> 6;
  const int lane = tid & 63;
  const int frow = lane & 15;
  const int kg   = lane >> 4;
  const int bn0  = blockIdx.x * 128;
  const int bm0  = blockIdx.y * 64;
  const size_t kofs = (size_t)blockIdx.z * 1024;

  // staging: chunk c (16B) -> LDS linear slot c; source k-chunk XOR-swizzled
  const unsigned short* gA[2];
  #pragma unroll
  for (int q = 0; q < 2; ++q) {
    int c = q * 256 + tid, r = c >> 3, kc = (c & 7) ^ (r & 7);
    gA[q] = Fb + (size_t)(bm0 + r) * ND + kofs + kc * 8;
  }
  const unsigned short* gB[4];
  #pragma unroll
  for (int q = 0; q < 4; ++q) {
    int c = q * 256 + tid, r = c >> 3, kc = (c & 7) ^ (r & 7);
    gB[q] = Mb + (size_t)(bn0 + r) * ND + kofs + kc * 8;
  }
  const int ldsb = wave * 512;   // elems; + q*2048 per instruction

  // fragment LDS offsets (elems), same swizzle
  int offA[4][2], offB[2][2];
  #pragma unroll
  for (int m = 0; m < 4; ++m)
    #pragma unroll
    for (int kf = 0; kf < 2; ++kf) {
      int r = m * 16 + frow, sc = (kf * 4 + kg) ^ (r & 7);
      offA[m][kf] = r * 64 + sc * 8;
    }
  #pragma unroll
  for (int n = 0; n < 2; ++n)
    #pragma unroll
    for (int kf = 0; kf < 2; ++kf) {
      int r = wave * 32 + n * 16 + frow, sc = (kf * 4 + kg) ^ (r & 7);
      offB[n][kf] = r * 64 + sc * 8;
    }

  floatx4 acc[4][2];
  #pragma unroll
  for (int m = 0; m < 4; ++m)
    #pragma unroll
    for (int n = 0; n < 2; ++n)
      #pragma unroll
      for (int r = 0; r < 4; ++r) acc[m][n][r] = 0.f;

  auto stage = [&](int buf, int kt) {
    int kk = kt * 64;
    #pragma unroll
    for (int q = 0; q < 2; ++q) GLOAD_LDS16(gA[q] + kk, &sA[buf][q * 2048 + ldsb]);
    #pragma unroll
    for (int q = 0; q < 4; ++q) GLOAD_LDS16(gB[q] + kk, &sB[buf][q * 2048 + ldsb]);
  };
  auto compute = [&](int buf) {
    short8 af[4][2], bf[2][2];
    #pragma unroll
    for (int m = 0; m < 4; ++m)
      #pragma unroll
      for (int kf = 0; kf < 2; ++kf) af[m][kf] = *(const short8*)&sA[buf][offA[m][kf]];
    #pragma unroll
    for (int n = 0; n < 2; ++n)
      #pragma unroll
      for (int kf = 0; kf < 2; ++kf) bf[n][kf] = *(const short8*)&sB[buf][offB[n][kf]];
    #pragma unroll
    for (int m = 0; m < 4; ++m)
      #pragma unroll
      for (int n = 0; n < 2; ++n) {
        acc[m][n] = __builtin_amdgcn_mfma_f32_16x16x32_bf16(af[m][0], bf[n][0], acc[m][n], 0, 0, 0);
        acc[m][n] = __builtin_amdgcn_mfma_f32_16x16x32_bf16(af[m][1], bf[n][1], acc[m][n], 0, 0, 0);
      }
  };

  stage(0, 0);
  __syncthreads();
  int cur = 0;
  for (int kt = 0; kt < 15; ++kt) {     // 1024/64 = 16 K-steps per slice
    stage(cur ^ 1, kt + 1);
    compute(cur);
    __syncthreads();
    cur ^= 1;
  }
  compute(cur);

  float* Sp = Sout + (size_t)blockIdx.z * ((size_t)NB * NP);
  #pragma unroll
  for (int m = 0; m < 4; ++m) {
    int row = bm0 + 16 * m + 4 * kg;             // C/D: row=(lane>>4)*4+r
    #pragma unroll
    for (int n = 0; n < 2; ++n) {
      int col = bn0 + wave * 32 + 16 * n + frow; // C/D: col=lane&15
      #pragma unroll
      for (int r = 0; r < 4; ++r)
        Sp[(size_t)(row + r) * NP + col] = acc[m][n][r];
    }
  }
}

// ---------------- per-row: intra CE, top-k threshold, inter loss ----------
// 1024 threads (16 waves), 8 elems/thread: p = (j<<10)|t  -> p%8 == t&7.
__global__ __launch_bounds__(1024)
void row_kernel(const float* __restrict__ S,
                const int* __restrict__ label,
                const int* __restrict__ camid,
                const int* __restrict__ pcl,
                const int* __restrict__ epoch_p,
                const int* __restrict__ ilep_p,
                const int* __restrict__ k_p,
                float* __restrict__ ce_out,
                float* __restrict__ li_out) {
  __shared__ float red[2][16];
  const int i = blockIdx.x, t = threadIdx.x, w = t >> 6;
  const bool l0 = (t & 63) == 0;
  int ph = 0;

  auto bred_sum = [&](float x) -> float {
    #pragma unroll
    for (int o = 32; o; o >>= 1) x += __shfl_xor(x, o);
    if (l0) red[ph][w] = x;
    __syncthreads();
    float s = 0.f;
    #pragma unroll
    for (int q = 0; q < 16; ++q) s += red[ph][q];
    ph ^= 1;
    return s;
  };
  auto bred_max = [&](float x) -> float {
    #pragma unroll
    for (int o = 32; o; o >>= 1) x = fmaxf(x, __shfl_xor(x, o));
    if (l0) red[ph][w] = x;
    __syncthreads();
    float s = NEG_INF_F;
    #pragma unroll
    for (int q = 0; q < 16; ++q) s = fmaxf(s, red[ph][q]);
    ph ^= 1;
    return s;
  };
  auto bred_uni = [&](float x) -> float {   // x already wave-uniform
    if (l0) red[ph][w] = x;
    __syncthreads();
    float s = 0.f;
    #pragma unroll
    for (int q = 0; q < 16; ++q) s += red[ph][q];
    ph ^= 1;
    return s;
  };

  const float* r0 = S + (size_t)i * NP;
  const float* r1 = r0 + (size_t)NB * NP;
  float v[8];
  #pragma unroll
  for (int j = 0; j < 8; ++j) v[j] = r0[(j << 10) | t] + r1[(j << 10) | t];

  const int camI = camid[i], clI = pcl[i], lab = label[i];
  const bool myCam = (t & 7) == camI;
  bool neg[8];
  #pragma unroll
  for (int j = 0; j < 8; ++j) neg[j] = (((j << 7) | (t >> 3)) != clI);

  // ---- intra-camera CE ----
  float m1 = NEG_INF_F;
  if (myCam) {
    #pragma unroll
    for (int j = 0; j < 8; ++j) m1 = fmaxf(m1, v[j]);
  }
  m1 = bred_max(m1);
  float s1 = 0.f, tg = 0.f;
  if (myCam) {
    #pragma unroll
    for (int j = 0; j < 8; ++j) s1 += __expf((v[j] - m1) * INV_TEMP);
  }
  #pragma unroll
  for (int j = 0; j < 8; ++j)
    if (((lab >> 10) == j) && (t == (lab & 1023))) tg = v[j];
  s1 = bred_sum(s1);
  tg = bred_sum(tg);
  if (t == 0) ce_out[i] = m1 * INV_TEMP + __logf(s1) - tg * INV_TEMP;

  // ---- inter-camera loss ----
  float li = 0.f;
  if (epoch_p[0] >= ilep_p[0]) {
    const int kneg = k_p[0];
    unsigned kk[8];
    #pragma unroll
    for (int j = 0; j < 8; ++j) {
      unsigned u = __float_as_uint(v[j]);
      kk[j] = (u & 0x80000000u) ? ~u : (u | 0x80000000u);
    }
    unsigned tstar = 0u;
    for (int b = 31; b >= 0; --b) {
      unsigned cand = tstar | (1u << b);
      int cw = 0;
      #pragma unroll
      for (int j = 0; j < 8; ++j)
        cw += __popcll(__ballot(neg[j] && (kk[j] >= cand)));
      float tot = bred_uni((float)cw);          // counts <= 8192, exact in f32
      if (tot >= (float)kneg) tstar = cand;
    }
    float thr = __uint_as_float((tstar & 0x80000000u) ? (tstar ^ 0x80000000u) : ~tstar);

    bool pos[8], keep[8];
    float m2 = NEG_INF_F;
    #pragma unroll
    for (int j = 0; j < 8; ++j) {
      pos[j]  = (!neg[j]) && ((t & 7) != camI);
      keep[j] = neg[j] && (v[j] < thr);          // strict <, ties dropped
      if (pos[j] || keep[j]) m2 = fmaxf(m2, v[j]);
    }
    m2 = bred_max(m2);
    float s2 = 0.f, sp = 0.f;
    int cw = 0;
    #pragma unroll
    for (int j = 0; j < 8; ++j) {
      if (pos[j] || keep[j]) s2 += __expf((v[j] - m2) * INV_TEMP);
      if (pos[j]) sp += v[j];
      cw += __popcll(__ballot(pos[j]));
    }
    s2 = bred_sum(s2);
    sp = bred_sum(sp);
    float card = bred_uni((float)cw);
    float lse2 = m2 * INV_TEMP + __logf(s2);
    li = (card > 0.f) ? -(sp * INV_TEMP - card * lse2) / card : 0.f;
  }
  if (t == 0) li_out[i] = li;
}

// ---------------- per-camera segment means -> scalar loss -----------------
__global__ void finalize_kernel(const float* __restrict__ ce,
                                const float* __restrict__ li,
                                const int* __restrict__ camid,
                                const int* __restrict__ epoch_p,
                                const int* __restrict__ ilep_p,
                                float* __restrict__ out) {
  __shared__ float cnt[8], sa[8], sb[8];
  const int t = threadIdx.x;
  if (t < 8) { cnt[t] = 0.f; sa[t] = 0.f; sb[t] = 0.f; }
  __syncthreads();
  const int c = camid[t];
  atomicAdd(&cnt[c], 1.f);
  atomicAdd(&sa[c], ce[t]);
  atomicAdd(&sb[c], li[t]);
  __syncthreads();
  if (t == 0) {
    const bool inter = epoch_p[0] >= ilep_p[0];
    float l = 0.f;
    for (int q = 0; q < 8; ++q)
      if (cnt[q] > 0.f) {
        l += sa[q] / cnt[q];
        if (inter) l += 0.5f * sb[q] / cnt[q];
      }
    out[0] = l;
  }
}

// ---------------- sequential EMA scatter update (scan semantics) ----------
__global__ __launch_bounds__(256)
void ema_kernel(const float* __restrict__ feat,
                const float* __restrict__ mem,
                const int* __restrict__ label,
                float* __restrict__ outmem) {
  __shared__ float red[4];
  const int b = blockIdx.x, t = threadIdx.x;
  const int y = label[b];
  for (int j = 0; j < b; ++j)
    if (label[j] == y) return;           // only first occurrence owns the chain
  float m[8];
  #pragma unroll
  for (int q = 0; q < 8; ++q) m[q] = mem[(size_t)y * ND + q * 256 + t];
  for (int i = b; i < NB; ++i) {
    if (label[i] != y) continue;         // block-uniform
    float ss = 0.f;
    #pragma unroll
    for (int q = 0; q < 8; ++q) {
      m[q] = 0.2f * m[q] + 0.8f * feat[(size_t)i * ND + q * 256 + t];
      ss += m[q] * m[q];
    }
    #pragma unroll
    for (int o = 32; o; o >>= 1) ss += __shfl_xor(ss, o);
    if ((t & 63) == 0) red[t >> 6] = ss;
    __syncthreads();
    ss = red[0] + red[1] + red[2] + red[3];
    __syncthreads();
    float inv = 1.f / sqrtf(ss);
    #pragma unroll
    for (int q = 0; q < 8; ++q) m[q] *= inv;
  }
  #pragma unroll
  for (int q = 0; q < 8; ++q) outmem[(size_t)y * ND + q * 256 + t] = m[q];
}

// --------------------------------------------------------------------------
extern "C" void kernel_launch(void* const* d_in, const int* in_sizes, int n_in,
                              void* d_out, int out_size, void* d_ws, size_t ws_size,
                              hipStream_t stream) {
  const float* feat = (const float*)d_in[0];
  const float* mem  = (const float*)d_in[1];
  const int* lab    = (const int*)d_in[2];
  const int* cam    = (const int*)d_in[3];
  const int* pcl    = (const int*)d_in[4];
  const int* ep     = (const int*)d_in[7];
  const int* ilep   = (const int*)d_in[8];
  const int* kp     = (const int*)d_in[9];
  float* out = (float*)d_out;

  // scratch in d_ws (~51.4 MB; ws is ~200+ MB per the 268 MB poison fill)
  char* ws = (char*)d_ws;
  unsigned short* Mb = (unsigned short*)(ws);               // 33,554,432 B
  unsigned short* Fb = (unsigned short*)(ws + 33554432);    //  1,048,576 B
  float*          S  = (float*)(ws + 34603008);             // 16,777,216 B
  float*          ce = (float*)(ws + 51380224);             //      1,024 B
  float*          li = (float*)(ws + 51381248);             //      1,024 B

  prep_kernel<<<8448, 256, 0, stream>>>(mem, feat, Mb, Fb, out + 1);
  gemm_kernel<<<dim3(NP / 128, NB / 64, 2), 256, 0, stream>>>(Fb, Mb, S);
  row_kernel<<<NB, 1024, 0, stream>>>(S, lab, cam, pcl, ep, ilep, kp, ce, li);
  finalize_kernel<<<1, 256, 0, stream>>>(ce, li, cam, ep, ilep, out);
  ema_kernel<<<NB, 256, 0, stream>>>(feat, mem, lab, out + 1);
}